// Round 1
// baseline (361.030 us; speedup 1.0000x reference)
//
#include <hip/hip_runtime.h>
#include <math.h>

// Problem constants (from reference setup_inputs)
#define BB 16
#define FF 256
#define TT 8192
#define KK 204   // int(256 * (1 - 0.2)) = 204 kept per row

// Kernel 1: compute the exact 0/1 mask, 16 blocks x 256 threads.
// Replicates: sig = sigmoid(w)+noise*0.05; keep iff (#strictly greater) < K
// (identical to x2 >= kth-largest, tie-inclusive); then straight-through
// binary == hard == ((clip((wta+1)*0.5,0,1)) > 0.5).
__global__ void mask_kernel(const float* __restrict__ w,
                            const float* __restrict__ noise,
                            float* __restrict__ mask) {
    __shared__ float vals[FF];
    const int b = blockIdx.x;
    const int f = threadIdx.x;
    float wv = w[f];
    float v = 1.0f / (1.0f + expf(-wv)) + noise[b * FF + f] * 0.05f;
    vals[f] = v;
    __syncthreads();
    int cnt = 0;
#pragma unroll 8
    for (int j = 0; j < FF; ++j) cnt += (vals[j] > v) ? 1 : 0;
    float wta = (cnt < KK) ? v : 0.0f;
    float p = (wta + 1.0f) * 0.5f;
    p = fminf(fmaxf(p, 0.0f), 1.0f);
    mask[b * FF + f] = (p > 0.5f) ? 1.0f : 0.0f;
}

// Kernel 2: streaming writer for both outputs (float4, grid-stride).
// Layout of d_out: masked_x (B,1,F,T) flat, then binary_mask (B,1,T,F) flat.
__global__ void apply_kernel(const float4* __restrict__ x4,
                             const float* __restrict__ mask,
                             float4* __restrict__ out4) {
    const int N4x = BB * FF * TT / 4;   // 8388608 float4 for masked_x
    const int total = 2 * N4x;          // + same count for binary_mask
    const int stride = gridDim.x * blockDim.x;
    const float4* __restrict__ m4 = (const float4*)mask;
    for (int i = blockIdx.x * blockDim.x + threadIdx.x; i < total; i += stride) {
        if (i < N4x) {
            // masked_x: row (b*F+f) = i / (T/4) ; T/4 = 2048 -> shift 11
            float m = mask[i >> 11];
            float4 xv = x4[i];
            float4 o;
            o.x = xv.x * m; o.y = xv.y * m; o.z = xv.z * m; o.w = xv.w * m;
            out4[i] = o;
        } else {
            int j = i - N4x;
            // binary_mask: b = j / (T*F/4) -> shift 19; f4 = j & 63
            out4[i] = m4[((j >> 19) << 6) | (j & 63)];
        }
    }
}

extern "C" void kernel_launch(void* const* d_in, const int* in_sizes, int n_in,
                              void* d_out, int out_size, void* d_ws, size_t ws_size,
                              hipStream_t stream) {
    const float* x     = (const float*)d_in[0];   // (16,1,256,8192)
    const float* w     = (const float*)d_in[1];   // (1,1,1,256)
    const float* noise = (const float*)d_in[2];   // (16,1,1,256)
    float* out  = (float*)d_out;
    float* mask = (float*)d_ws;                   // 16 KB scratch

    mask_kernel<<<BB, FF, 0, stream>>>(w, noise, mask);

    const int total4 = 2 * BB * FF * TT / 4;      // 16,777,216 float4
    const int threads = 256;
    const int blocks = 16384;                     // grid-stride, ~4 float4/thread
    (void)total4; (void)out_size; (void)ws_size; (void)n_in; (void)in_sizes;
    apply_kernel<<<blocks, threads, 0, stream>>>((const float4*)x, mask, (float4*)out);
}